// Round 4
// baseline (370.184 us; speedup 1.0000x reference)
//
#include <hip/hip_runtime.h>
#include <math.h>

#define BB 8
#define SS 4096
#define HH 1024
#define EE 256
#define KK 64
#define HQ 256
#define NEGF -1e30f

typedef short bf16x8 __attribute__((ext_vector_type(8)));
typedef float f32x4  __attribute__((ext_vector_type(4)));

__device__ inline short f2bf(float x) {
    unsigned u = __float_as_uint(x);
    unsigned r = (u + 0x7fffu + ((u >> 16) & 1u)) >> 16;   // RNE
    return (short)r;
}

// pack two f32 into two bf16 (round-half-up): 4 VALU per pair
__device__ inline unsigned pk2bf(float lo, float hi) {
    unsigned a = __float_as_uint(lo) + 0x8000u;
    unsigned b = __float_as_uint(hi) + 0x8000u;
    return (a >> 16) | (b & 0xffff0000u);
}

// w1s[kb][n][kk] = bf16(w1[(kb*32+kk)*HQ + n]); kb in [0,32), n in [0,256), kk in [0,32)
__global__ __launch_bounds__(256) void convert_w1_kernel(
    const float* __restrict__ w1, short* __restrict__ w1s)
{
    const int kb = blockIdx.x, n = threadIdx.x;
    for (int kk = 0; kk < 32; kk++)
        w1s[kb * 8192 + n * 32 + kk] = f2bf(w1[(kb * 32 + kk) * HQ + n]);
}

// Streaming MFMA score: 64 rows/WG, wave wv owns cols [64wv,64wv+64).
// NO LDS staging, NO barriers in the K-loop: A fragments are 32 B contiguous
// f32 (converted in-register), B fragments are 16 B contiguous bf16 in the
// blocked w1s layout. Loads pipeline freely across K-iterations.
__global__ __launch_bounds__(256) void mfma_score2_kernel(
    const float* __restrict__ X, const short* __restrict__ w1s,
    const float* __restrict__ b1, const float* __restrict__ w2,
    const float* __restrict__ b2, float* __restrict__ out)
{
    __shared__ float part[4][64];
    const int t = threadIdx.x;
    const int wv = t >> 6, lane = t & 63, lo = lane & 15, q = lane >> 4;
    const long row0 = (long)blockIdx.x * 64;

    f32x4 acc[4][4];
#pragma unroll
    for (int i = 0; i < 4; i++)
#pragma unroll
        for (int j = 0; j < 4; j++) acc[i][j] = (f32x4){0.f, 0.f, 0.f, 0.f};

    const float* xp = X + (row0 + lo) * HH + q * 8;       // + rt*16*HH + kb*32
    const short* wp = w1s + (wv * 64 + lo) * 32 + q * 8;  // + kb*8192 + ct*512

    for (int kb = 0; kb < 32; kb++) {
        bf16x8 bfr[4];
#pragma unroll
        for (int ct = 0; ct < 4; ct++)
            bfr[ct] = *(const bf16x8*)(wp + kb * 8192 + ct * 512);
        bf16x8 af[4];
#pragma unroll
        for (int rt = 0; rt < 4; rt++) {
            const float4* p = (const float4*)(xp + (long)rt * 16 * HH + kb * 32);
            float4 v0 = p[0], v1 = p[1];
            union { unsigned u[4]; bf16x8 h; } c;
            c.u[0] = pk2bf(v0.x, v0.y);
            c.u[1] = pk2bf(v0.z, v0.w);
            c.u[2] = pk2bf(v1.x, v1.y);
            c.u[3] = pk2bf(v1.z, v1.w);
            af[rt] = c.h;
        }
#pragma unroll
        for (int rt = 0; rt < 4; rt++)
#pragma unroll
            for (int ct = 0; ct < 4; ct++)
                acc[rt][ct] = __builtin_amdgcn_mfma_f32_16x16x32_bf16(
                    af[rt], bfr[ct], acc[rt][ct], 0, 0, 0);
    }

    // epilogue: rowpart[rt][reg] = sum_c tanh(acc + b1[c]) * w2[c]
    float rowpart[4][4];
#pragma unroll
    for (int rt = 0; rt < 4; rt++)
#pragma unroll
        for (int r = 0; r < 4; r++) rowpart[rt][r] = 0.f;
#pragma unroll
    for (int ct = 0; ct < 4; ct++) {
        const int c = wv * 64 + ct * 16 + lo;
        const float b1c = b1[c], w2c = w2[c];
#pragma unroll
        for (int rt = 0; rt < 4; rt++)
#pragma unroll
            for (int r = 0; r < 4; r++)
                rowpart[rt][r] += tanhf(acc[rt][ct][r] + b1c) * w2c;
    }
#pragma unroll
    for (int rt = 0; rt < 4; rt++)
#pragma unroll
        for (int r = 0; r < 4; r++) {
            float v = rowpart[rt][r];
            v += __shfl_down(v, 8, 64);
            v += __shfl_down(v, 4, 64);
            v += __shfl_down(v, 2, 64);
            v += __shfl_down(v, 1, 64);
            rowpart[rt][r] = v;   // valid where lo==0
        }
    if (lo == 0)
#pragma unroll
        for (int rt = 0; rt < 4; rt++)
#pragma unroll
            for (int r = 0; r < 4; r++)
                part[wv][rt * 16 + q * 4 + r] = rowpart[rt][r];
    __syncthreads();
    if (t < 64)
        out[row0 + t] = part[0][t] + part[1][t] + part[2][t] + part[3][t] + b2[0];
}

// Per (b,k): masked max + denom over contiguous range; write normalized token
// weights wtok (0 for masked/invalid/empty).
__global__ __launch_bounds__(256) void block_stats_kernel(
    const float* __restrict__ scores, const int* __restrict__ mask,
    const int* __restrict__ bnd, float* __restrict__ bmax, float* __restrict__ bden,
    float* __restrict__ wtok)
{
    const int b = blockIdx.x >> 6, k = blockIdx.x & 63;
    const int start = bnd[b * KK + k];
    const int end = (k == KK - 1) ? SS : bnd[b * KK + k + 1];
    const int tid = threadIdx.x;
    __shared__ float r[4];
    __shared__ float mshared, dshared;

    float m = NEGF;
    for (int s = start + tid; s < end; s += 256)
        if (mask[b * SS + s] == 1) m = fmaxf(m, scores[b * SS + s]);
    for (int off = 32; off > 0; off >>= 1) m = fmaxf(m, __shfl_down(m, off, 64));
    if ((tid & 63) == 0) r[tid >> 6] = m;
    __syncthreads();
    if (tid == 0) mshared = fmaxf(fmaxf(r[0], r[1]), fmaxf(r[2], r[3]));
    __syncthreads();
    m = mshared;

    float d = 0.f;
    for (int s = start + tid; s < end; s += 256)
        if (mask[b * SS + s] == 1) d += expf(scores[b * SS + s] - m);
    for (int off = 32; off > 0; off >>= 1) d += __shfl_down(d, off, 64);
    __syncthreads();
    if ((tid & 63) == 0) r[tid >> 6] = d;
    __syncthreads();
    if (tid == 0) {
        float den = r[0] + r[1] + r[2] + r[3];
        bmax[blockIdx.x] = m; bden[blockIdx.x] = den;
        dshared = (den > 0.f) ? 1.f / fmaxf(den, 1e-30f) : 0.f;
    }
    __syncthreads();
    const float inv = dshared;
    for (int s = start + tid; s < end; s += 256)
        wtok[b * SS + s] = (mask[b * SS + s] == 1) ? expf(scores[b * SS + s] - m) * inv : 0.f;
}

// Weighted accumulation: grid = B x (S/16); thread t owns h=4t..4t+3 (float4,
// 1 vmem/token). Branch-light; atomicAdd flush at block transitions.
#define TCH 16
__global__ __launch_bounds__(256) void block_embed3_kernel(
    const float* __restrict__ hidden, const float* __restrict__ wtok,
    const int* __restrict__ bnd, float* __restrict__ embed)
{
    const int b = blockIdx.x >> 8;          // 4096/16 = 256 chunks per batch
    const int ch = blockIdx.x & 255;
    const int t = threadIdx.x;
    __shared__ int bsh[KK];
    if (t < KK) bsh[t] = bnd[b * KK + t];
    __syncthreads();

    const int s0 = ch * TCH;
    int cur = -1;
#pragma unroll
    for (int i = 0; i < KK; i++) cur = (bsh[i] <= s0) ? i : cur;

    float4 a = {0.f, 0.f, 0.f, 0.f};
    bool any = false;
    const float4* hp = (const float4*)(hidden + ((long)b * SS + s0) * HH) + t;
    const float* wt = wtok + b * SS + s0;

    for (int i = 0; i < TCH; i++) {
        const int s = s0 + i;
        while (cur + 1 < KK && bsh[cur + 1] <= s) {
            if (any) {
                float* e = embed + ((long)b * KK + cur) * HH + t * 4;
                atomicAdd(e, a.x); atomicAdd(e + 1, a.y);
                atomicAdd(e + 2, a.z); atomicAdd(e + 3, a.w);
                a = (float4){0.f, 0.f, 0.f, 0.f}; any = false;
            }
            cur++;
        }
        const float w = wt[i];
        const float4 h = hp[i * (HH / 4)];
        a.x = fmaf(w, h.x, a.x); a.y = fmaf(w, h.y, a.y);
        a.z = fmaf(w, h.z, a.z); a.w = fmaf(w, h.w, a.w);
        any = any | (w != 0.f);
    }
    if (any) {
        float* e = embed + ((long)b * KK + cur) * HH + t * 4;
        atomicAdd(e, a.x); atomicAdd(e + 1, a.y);
        atomicAdd(e + 2, a.z); atomicAdd(e + 3, a.w);
    }
}

// finalize A (grid B): block softmax + func[b][h] (float4 per thread)
__global__ __launch_bounds__(256) void finalize_a_kernel(
    const float* __restrict__ embed, const float* __restrict__ bscores,
    const float* __restrict__ bden, float* __restrict__ func)
{
    const int b = blockIdx.x, t = threadIdx.x;
    __shared__ float bw[KK];
    if (t < KK) {   // wave 0
        float s = (bden[b * KK + t] > 0.f) ? bscores[b * KK + t] : NEGF;
        float m = s;
        for (int off = 32; off > 0; off >>= 1) m = fmaxf(m, __shfl_xor(m, off, 64));
        float e = expf(s - m);
        float d = e;
        for (int off = 32; off > 0; off >>= 1) d += __shfl_xor(d, off, 64);
        bw[t] = e / d;
    }
    __syncthreads();
    float4 f = {0.f, 0.f, 0.f, 0.f};
    const float4* ep = (const float4*)(embed + (long)b * KK * HH) + t;
#pragma unroll 8
    for (int k = 0; k < KK; k++) {
        const float w = bw[k];
        const float4 h = ep[k * (HH / 4)];
        f.x = fmaf(w, h.x, f.x); f.y = fmaf(w, h.y, f.y);
        f.z = fmaf(w, h.z, f.z); f.w = fmaf(w, h.w, f.w);
    }
    *((float4*)(func + b * HH) + t) = f;
}

// finalize B (grid B*8): partial GEMV over a 128-row h-slice of out_w
__global__ __launch_bounds__(256) void finalize_b_kernel(
    const float* __restrict__ func, const float* __restrict__ out_w,
    float* __restrict__ osum)
{
    const int b = blockIdx.x >> 3, hc = blockIdx.x & 7;
    const int t = threadIdx.x;
    __shared__ float fsh[128];
    if (t < 128) fsh[t] = func[b * HH + hc * 128 + t];
    __syncthreads();
    float acc = 0.f;
    const float* wp = out_w + (long)(hc * 128) * EE + t;
#pragma unroll 8
    for (int h = 0; h < 128; h++)
        acc = fmaf(fsh[h], wp[(long)h * EE], acc);
    atomicAdd(&osum[b * EE + t], acc);
}

// finalize C (grid B): bias + L2 normalize
__global__ __launch_bounds__(256) void finalize_c_kernel(
    const float* __restrict__ osum, const float* __restrict__ out_b,
    float* __restrict__ outp)
{
    const int b = blockIdx.x, t = threadIdx.x;
    __shared__ float r4[4];
    float o = osum[b * EE + t] + out_b[t];
    float sq = o * o;
    for (int off = 32; off > 0; off >>= 1) sq += __shfl_down(sq, off, 64);
    if ((t & 63) == 0) r4[t >> 6] = sq;
    __syncthreads();
    const float nrm = sqrtf(r4[0] + r4[1] + r4[2] + r4[3]);
    outp[b * EE + t] = o / fmaxf(nrm, 1e-12f);
}

extern "C" void kernel_launch(void* const* d_in, const int* in_sizes, int n_in,
                              void* d_out, int out_size, void* d_ws, size_t ws_size,
                              hipStream_t stream) {
    const float* hidden  = (const float*)d_in[0];
    const int*   mask    = (const int*)  d_in[1];
    const int*   bnd     = (const int*)  d_in[2];
    const float* tok_w1  = (const float*)d_in[3];
    const float* tok_b1  = (const float*)d_in[4];
    const float* tok_w2  = (const float*)d_in[5];
    const float* tok_b2  = (const float*)d_in[6];
    const float* blk_w1  = (const float*)d_in[7];
    const float* blk_b1  = (const float*)d_in[8];
    const float* blk_w2  = (const float*)d_in[9];
    const float* blk_b2  = (const float*)d_in[10];
    const float* out_w   = (const float*)d_in[11];
    const float* out_b   = (const float*)d_in[12];

    float* ws      = (float*)d_ws;
    float* wtok    = ws;                     // [32768]
    float* embed   = ws + 32768;             // [524288]
    float* osum    = ws + 557056;            // [2048]
    float* scores  = ws + 559104;            // [32768]
    float* bmax    = ws + 591872;            // [512]
    float* bden    = ws + 592384;            // [512]
    float* bscores = ws + 592896;            // [512]
    float* func    = ws + 593408;            // [8192]
    short* w1s     = (short*)(ws + 601600);  // [262144] bf16 (reused tok->blk)

    // zero wtok + embed + osum (contiguous prefix)
    hipMemsetAsync(d_ws, 0, (size_t)559104 * 4, stream);

    convert_w1_kernel<<<32, 256, 0, stream>>>(tok_w1, w1s);
    mfma_score2_kernel<<<BB * SS / 64, 256, 0, stream>>>(
        hidden, w1s, tok_b1, tok_w2, tok_b2, scores);
    block_stats_kernel<<<BB * KK, 256, 0, stream>>>(scores, mask, bnd, bmax, bden, wtok);
    block_embed3_kernel<<<BB * SS / TCH, 256, 0, stream>>>(hidden, wtok, bnd, embed);
    convert_w1_kernel<<<32, 256, 0, stream>>>(blk_w1, w1s);   // stream-ordered reuse
    mfma_score2_kernel<<<BB * KK / 64, 256, 0, stream>>>(
        embed, w1s, blk_b1, blk_w2, blk_b2, bscores);
    finalize_a_kernel<<<BB, 256, 0, stream>>>(embed, bscores, bden, func);
    finalize_b_kernel<<<BB * 8, 256, 0, stream>>>(func, out_w, osum);
    finalize_c_kernel<<<BB, 256, 0, stream>>>(osum, out_b, (float*)d_out);
}

// Round 5
// 317.252 us; speedup vs baseline: 1.1668x; 1.1668x over previous
//
#include <hip/hip_runtime.h>
#include <math.h>

#define BB 8
#define SS 4096
#define HH 1024
#define EE 256
#define KK 64
#define HQ 256
#define NEGF -1e30f

typedef short bf16x8 __attribute__((ext_vector_type(8)));
typedef float f32x4  __attribute__((ext_vector_type(4)));

__device__ inline short f2bf(float x) {
    unsigned u = __float_as_uint(x);
    unsigned r = (u + 0x7fffu + ((u >> 16) & 1u)) >> 16;   // RNE
    return (short)r;
}

// pack two f32 into two bf16 (round-half-up)
__device__ inline unsigned pk2bf(float lo, float hi) {
    unsigned a = __float_as_uint(lo) + 0x8000u;
    unsigned b = __float_as_uint(hi) + 0x8000u;
    return (a >> 16) | (b & 0xffff0000u);
}

// w1s[kb][n][kk] = bf16(w1[(kb*32+kk)*HQ + n]); kb in [0,32), n in [0,256), kk in [0,32)
__global__ __launch_bounds__(256) void convert_w1_kernel(
    const float* __restrict__ w1, short* __restrict__ w1s)
{
    const int kb = blockIdx.x, n = threadIdx.x;
    for (int kk = 0; kk < 32; kk++)
        w1s[kb * 8192 + n * 32 + kk] = f2bf(w1[(kb * 32 + kk) * HQ + n]);
}

// Row scores: 64 rows/WG x 256 cols. A (X tile) double-buffered in LDS,
// fragment-ordered (thread t stages chunk t -> zero bank conflicts), shared by
// all 4 waves. B (w1s) streams from global per wave (private cols, blocked
// layout, 16B contiguous fragments). ONE barrier per k-iteration.
__global__ __launch_bounds__(256) void mfma_score3_kernel(
    const float* __restrict__ X, const short* __restrict__ w1s,
    const float* __restrict__ b1, const float* __restrict__ w2,
    const float* __restrict__ b2, float* __restrict__ out)
{
    __shared__ __attribute__((aligned(16))) short As[2][2048];  // 2 x 4 KB bf16
    __shared__ float part[4][64];

    const int t = threadIdx.x;
    const int wv = t >> 6, lane = t & 63, lo = lane & 15, q = lane >> 4;
    const long row0 = (long)blockIdx.x * 64;

    f32x4 acc[4][4];
#pragma unroll
    for (int i = 0; i < 4; i++)
#pragma unroll
        for (int j = 0; j < 4; j++) acc[i][j] = (f32x4){0.f, 0.f, 0.f, 0.f};

    // staging: thread t handles (rt=wv, q, lo): row = wv*16+lo, k = kb*32+q*8
    const float* xs = X + (row0 + wv * 16 + lo) * HH + q * 8;
    // B: wave wv, fragment ct: lane(q,lo) -> n = wv*64+ct*16+lo, k = kb*32+q*8
    const short* wp = w1s + (wv * 64 + lo) * 32 + q * 8;

    // prologue: stage kb=0 into buf0, load B frags for kb=0
    {
        const float4* p = (const float4*)xs;
        float4 v0 = p[0], v1 = p[1];
        union { unsigned u[4]; bf16x8 h; } c;
        c.u[0] = pk2bf(v0.x, v0.y); c.u[1] = pk2bf(v0.z, v0.w);
        c.u[2] = pk2bf(v1.x, v1.y); c.u[3] = pk2bf(v1.z, v1.w);
        *(bf16x8*)(&As[0][t * 8]) = c.h;
    }
    bf16x8 bA[4], bB[4];
#pragma unroll
    for (int ct = 0; ct < 4; ct++)
        bA[ct] = *(const bf16x8*)(wp + ct * 512);
    __syncthreads();

    for (int kb = 0; kb < 32; kb += 2) {
        {   // stage kb+1 -> buf1 + load bB(kb+1); compute kb from buf0 with bA
            const int k1 = kb + 1;
            const float4* p = (const float4*)(xs + k1 * 32);
            float4 v0 = p[0], v1 = p[1];
#pragma unroll
            for (int ct = 0; ct < 4; ct++)
                bB[ct] = *(const bf16x8*)(wp + k1 * 8192 + ct * 512);
            bf16x8 af[4];
#pragma unroll
            for (int rt = 0; rt < 4; rt++)
                af[rt] = *(bf16x8*)(&As[0][(rt * 64 + q * 16 + lo) * 8]);
#pragma unroll
            for (int rt = 0; rt < 4; rt++)
#pragma unroll
                for (int ct = 0; ct < 4; ct++)
                    acc[rt][ct] = __builtin_amdgcn_mfma_f32_16x16x32_bf16(
                        af[rt], bA[ct], acc[rt][ct], 0, 0, 0);
            union { unsigned u[4]; bf16x8 h; } c;
            c.u[0] = pk2bf(v0.x, v0.y); c.u[1] = pk2bf(v0.z, v0.w);
            c.u[2] = pk2bf(v1.x, v1.y); c.u[3] = pk2bf(v1.z, v1.w);
            *(bf16x8*)(&As[1][t * 8]) = c.h;
        }
        __syncthreads();
        {   // stage kb+2 -> buf0 + load bA(kb+2); compute kb+1 from buf1 with bB
            const int k2 = (kb + 2 < 32) ? kb + 2 : 31;   // clamped dummy on last iter
            const float4* p = (const float4*)(xs + k2 * 32);
            float4 v0 = p[0], v1 = p[1];
#pragma unroll
            for (int ct = 0; ct < 4; ct++)
                bA[ct] = *(const bf16x8*)(wp + k2 * 8192 + ct * 512);
            bf16x8 af[4];
#pragma unroll
            for (int rt = 0; rt < 4; rt++)
                af[rt] = *(bf16x8*)(&As[1][(rt * 64 + q * 16 + lo) * 8]);
#pragma unroll
            for (int rt = 0; rt < 4; rt++)
#pragma unroll
                for (int ct = 0; ct < 4; ct++)
                    acc[rt][ct] = __builtin_amdgcn_mfma_f32_16x16x32_bf16(
                        af[rt], bB[ct], acc[rt][ct], 0, 0, 0);
            union { unsigned u[4]; bf16x8 h; } c;
            c.u[0] = pk2bf(v0.x, v0.y); c.u[1] = pk2bf(v0.z, v0.w);
            c.u[2] = pk2bf(v1.x, v1.y); c.u[3] = pk2bf(v1.z, v1.w);
            *(bf16x8*)(&As[0][t * 8]) = c.h;
        }
        __syncthreads();
    }

    // epilogue: rowpart[rt][r] = sum_c tanh(acc + b1[c]) * w2[c]
    float rowpart[4][4];
#pragma unroll
    for (int rt = 0; rt < 4; rt++)
#pragma unroll
        for (int r = 0; r < 4; r++) rowpart[rt][r] = 0.f;
#pragma unroll
    for (int ct = 0; ct < 4; ct++) {
        const int c = wv * 64 + ct * 16 + lo;
        const float b1c = b1[c], w2c = w2[c];
#pragma unroll
        for (int rt = 0; rt < 4; rt++)
#pragma unroll
            for (int r = 0; r < 4; r++)
                rowpart[rt][r] += tanhf(acc[rt][ct][r] + b1c) * w2c;
    }
#pragma unroll
    for (int rt = 0; rt < 4; rt++)
#pragma unroll
        for (int r = 0; r < 4; r++) {
            float v = rowpart[rt][r];
            v += __shfl_down(v, 8, 64);
            v += __shfl_down(v, 4, 64);
            v += __shfl_down(v, 2, 64);
            v += __shfl_down(v, 1, 64);
            rowpart[rt][r] = v;   // valid where lo==0
        }
    if (lo == 0)
#pragma unroll
        for (int rt = 0; rt < 4; rt++)
#pragma unroll
            for (int r = 0; r < 4; r++)
                part[wv][rt * 16 + q * 4 + r] = rowpart[rt][r];
    __syncthreads();
    if (t < 64)
        out[row0 + t] = part[0][t] + part[1][t] + part[2][t] + part[3][t] + b2[0];
}

// Per (b,k): masked max + denom over contiguous range; write normalized token
// weights wtok (0 for masked/invalid/empty).
__global__ __launch_bounds__(256) void block_stats_kernel(
    const float* __restrict__ scores, const int* __restrict__ mask,
    const int* __restrict__ bnd, float* __restrict__ bmax, float* __restrict__ bden,
    float* __restrict__ wtok)
{
    const int b = blockIdx.x >> 6, k = blockIdx.x & 63;
    const int start = bnd[b * KK + k];
    const int end = (k == KK - 1) ? SS : bnd[b * KK + k + 1];
    const int tid = threadIdx.x;
    __shared__ float r[4];
    __shared__ float mshared, dshared;

    float m = NEGF;
    for (int s = start + tid; s < end; s += 256)
        if (mask[b * SS + s] == 1) m = fmaxf(m, scores[b * SS + s]);
    for (int off = 32; off > 0; off >>= 1) m = fmaxf(m, __shfl_down(m, off, 64));
    if ((tid & 63) == 0) r[tid >> 6] = m;
    __syncthreads();
    if (tid == 0) mshared = fmaxf(fmaxf(r[0], r[1]), fmaxf(r[2], r[3]));
    __syncthreads();
    m = mshared;

    float d = 0.f;
    for (int s = start + tid; s < end; s += 256)
        if (mask[b * SS + s] == 1) d += expf(scores[b * SS + s] - m);
    for (int off = 32; off > 0; off >>= 1) d += __shfl_down(d, off, 64);
    __syncthreads();
    if ((tid & 63) == 0) r[tid >> 6] = d;
    __syncthreads();
    if (tid == 0) {
        float den = r[0] + r[1] + r[2] + r[3];
        bmax[blockIdx.x] = m; bden[blockIdx.x] = den;
        dshared = (den > 0.f) ? 1.f / fmaxf(den, 1e-30f) : 0.f;
    }
    __syncthreads();
    const float inv = dshared;
    for (int s = start + tid; s < end; s += 256)
        wtok[b * SS + s] = (mask[b * SS + s] == 1) ? expf(scores[b * SS + s] - m) * inv : 0.f;
}

// Weighted accumulation (r3 version): grid = B x (S/32); thread t owns
// h = t, t+256, t+512, t+768 (lane-coalesced atomics at flush).
#define TCH 32
__global__ __launch_bounds__(256) void block_embed2_kernel(
    const float* __restrict__ hidden, const float* __restrict__ wtok,
    const int* __restrict__ bnd, float* __restrict__ embed)
{
    const int b = blockIdx.x >> 7;
    const int ch = blockIdx.x & 127;
    const int t = threadIdx.x;
    __shared__ int bsh[KK];
    if (t < KK) bsh[t] = bnd[b * KK + t];
    __syncthreads();

    const int s0 = ch * TCH, s1 = s0 + TCH;
    int cur = -1;
    for (int i = 0; i < KK; i++) if (bsh[i] <= s0) cur = i;

    float a0 = 0.f, a1 = 0.f, a2 = 0.f, a3 = 0.f;
    bool any = false;
    for (int s = s0; s < s1; s++) {
        while (cur + 1 < KK && bsh[cur + 1] <= s) {
            if (any) {
                float* e = embed + ((long)b * KK + cur) * HH;
                atomicAdd(e + t, a0); atomicAdd(e + t + 256, a1);
                atomicAdd(e + t + 512, a2); atomicAdd(e + t + 768, a3);
                a0 = a1 = a2 = a3 = 0.f; any = false;
            }
            cur++;
        }
        if (cur < 0) continue;
        const float w = wtok[b * SS + s];
        if (w != 0.f) {
            const float* hr = hidden + ((long)b * SS + s) * HH;
            a0 = fmaf(w, hr[t], a0);
            a1 = fmaf(w, hr[t + 256], a1);
            a2 = fmaf(w, hr[t + 512], a2);
            a3 = fmaf(w, hr[t + 768], a3);
            any = true;
        }
    }
    if (any) {
        float* e = embed + ((long)b * KK + cur) * HH;
        atomicAdd(e + t, a0); atomicAdd(e + t + 256, a1);
        atomicAdd(e + t + 512, a2); atomicAdd(e + t + 768, a3);
    }
}

// finalize A (grid B): block softmax + func[b][h] (float4 per thread)
__global__ __launch_bounds__(256) void finalize_a_kernel(
    const float* __restrict__ embed, const float* __restrict__ bscores,
    const float* __restrict__ bden, float* __restrict__ func)
{
    const int b = blockIdx.x, t = threadIdx.x;
    __shared__ float bw[KK];
    if (t < KK) {   // wave 0
        float s = (bden[b * KK + t] > 0.f) ? bscores[b * KK + t] : NEGF;
        float m = s;
        for (int off = 32; off > 0; off >>= 1) m = fmaxf(m, __shfl_xor(m, off, 64));
        float e = expf(s - m);
        float d = e;
        for (int off = 32; off > 0; off >>= 1) d += __shfl_xor(d, off, 64);
        bw[t] = e / d;
    }
    __syncthreads();
    float4 f = {0.f, 0.f, 0.f, 0.f};
    const float4* ep = (const float4*)(embed + (long)b * KK * HH) + t;
#pragma unroll 8
    for (int k = 0; k < KK; k++) {
        const float w = bw[k];
        const float4 h = ep[k * (HH / 4)];
        f.x = fmaf(w, h.x, f.x); f.y = fmaf(w, h.y, f.y);
        f.z = fmaf(w, h.z, f.z); f.w = fmaf(w, h.w, f.w);
    }
    *((float4*)(func + b * HH) + t) = f;
}

// finalize B (grid B*8): partial GEMV over a 128-row h-slice of out_w
__global__ __launch_bounds__(256) void finalize_b_kernel(
    const float* __restrict__ func, const float* __restrict__ out_w,
    float* __restrict__ osum)
{
    const int b = blockIdx.x >> 3, hc = blockIdx.x & 7;
    const int t = threadIdx.x;
    __shared__ float fsh[128];
    if (t < 128) fsh[t] = func[b * HH + hc * 128 + t];
    __syncthreads();
    float acc = 0.f;
    const float* wp = out_w + (long)(hc * 128) * EE + t;
#pragma unroll 8
    for (int h = 0; h < 128; h++)
        acc = fmaf(fsh[h], wp[(long)h * EE], acc);
    atomicAdd(&osum[b * EE + t], acc);
}

// finalize C (grid B): bias + L2 normalize
__global__ __launch_bounds__(256) void finalize_c_kernel(
    const float* __restrict__ osum, const float* __restrict__ out_b,
    float* __restrict__ outp)
{
    const int b = blockIdx.x, t = threadIdx.x;
    __shared__ float r4[4];
    float o = osum[b * EE + t] + out_b[t];
    float sq = o * o;
    for (int off = 32; off > 0; off >>= 1) sq += __shfl_down(sq, off, 64);
    if ((t & 63) == 0) r4[t >> 6] = sq;
    __syncthreads();
    const float nrm = sqrtf(r4[0] + r4[1] + r4[2] + r4[3]);
    outp[b * EE + t] = o / fmaxf(nrm, 1e-12f);
}

extern "C" void kernel_launch(void* const* d_in, const int* in_sizes, int n_in,
                              void* d_out, int out_size, void* d_ws, size_t ws_size,
                              hipStream_t stream) {
    const float* hidden  = (const float*)d_in[0];
    const int*   mask    = (const int*)  d_in[1];
    const int*   bnd     = (const int*)  d_in[2];
    const float* tok_w1  = (const float*)d_in[3];
    const float* tok_b1  = (const float*)d_in[4];
    const float* tok_w2  = (const float*)d_in[5];
    const float* tok_b2  = (const float*)d_in[6];
    const float* blk_w1  = (const float*)d_in[7];
    const float* blk_b1  = (const float*)d_in[8];
    const float* blk_w2  = (const float*)d_in[9];
    const float* blk_b2  = (const float*)d_in[10];
    const float* out_w   = (const float*)d_in[11];
    const float* out_b   = (const float*)d_in[12];

    float* ws      = (float*)d_ws;
    float* wtok    = ws;                     // [32768]
    float* embed   = ws + 32768;             // [524288]
    float* osum    = ws + 557056;            // [2048]
    float* scores  = ws + 559104;            // [32768]
    float* bmax    = ws + 591872;            // [512]
    float* bden    = ws + 592384;            // [512]
    float* bscores = ws + 592896;            // [512]
    float* func    = ws + 593408;            // [8192]
    short* w1s     = (short*)(ws + 601600);  // [262144] bf16 (reused tok->blk)

    // zero wtok + embed + osum (contiguous prefix)
    hipMemsetAsync(d_ws, 0, (size_t)559104 * 4, stream);

    convert_w1_kernel<<<32, 256, 0, stream>>>(tok_w1, w1s);
    mfma_score3_kernel<<<BB * SS / 64, 256, 0, stream>>>(
        hidden, w1s, tok_b1, tok_w2, tok_b2, scores);
    block_stats_kernel<<<BB * KK, 256, 0, stream>>>(scores, mask, bnd, bmax, bden, wtok);
    block_embed2_kernel<<<BB * SS / TCH, 256, 0, stream>>>(hidden, wtok, bnd, embed);
    convert_w1_kernel<<<32, 256, 0, stream>>>(blk_w1, w1s);   // stream-ordered reuse
    mfma_score3_kernel<<<BB * KK / 64, 256, 0, stream>>>(
        embed, w1s, blk_b1, blk_w2, blk_b2, bscores);
    finalize_a_kernel<<<BB, 256, 0, stream>>>(embed, bscores, bden, func);
    finalize_b_kernel<<<BB * 8, 256, 0, stream>>>(func, out_w, osum);
    finalize_c_kernel<<<BB, 256, 0, stream>>>(osum, out_b, (float*)d_out);
}

// Round 6
// 300.737 us; speedup vs baseline: 1.2309x; 1.0549x over previous
//
#include <hip/hip_runtime.h>
#include <math.h>
#include <limits.h>

#define BB 8
#define SS 4096
#define HH 1024
#define EE 256
#define KK 64
#define HQ 256
#define NEGF -1e30f

typedef short bf16x8 __attribute__((ext_vector_type(8)));
typedef float f32x4  __attribute__((ext_vector_type(4)));

__device__ inline short f2bf(float x) {
    unsigned u = __float_as_uint(x);
    unsigned r = (u + 0x7fffu + ((u >> 16) & 1u)) >> 16;   // RNE
    return (short)r;
}

// pack two f32 into two bf16 (round-half-up)
__device__ inline unsigned pk2bf(float lo, float hi) {
    unsigned a = __float_as_uint(lo) + 0x8000u;
    unsigned b = __float_as_uint(hi) + 0x8000u;
    return (a >> 16) | (b & 0xffff0000u);
}

// Both weight conversions in one kernel. dst[kb][n][kk] = bf16(src[(kb*32+kk)*HQ+n])
__global__ __launch_bounds__(256) void convert_both_kernel(
    const float* __restrict__ tok_w1, const float* __restrict__ blk_w1,
    short* __restrict__ w1s_tok, short* __restrict__ w1s_blk)
{
    const int kb = blockIdx.x & 31, which = blockIdx.x >> 5;
    const float* src = which ? blk_w1 : tok_w1;
    short* dst = which ? w1s_blk : w1s_tok;
    const int n = threadIdx.x;
    for (int kk = 0; kk < 32; kk++)
        dst[kb * 8192 + n * 32 + kk] = f2bf(src[(kb * 32 + kk) * HQ + n]);
}

// Row scores: 32 rows/WG x 256 cols -> grid = M/32 (1024 for tokens: 4 WG/CU).
// A (X tile) double-buffered in LDS, fragment-ordered (zero conflicts), shared
// by 4 waves; B streams from global (blocked w1s layout, 16B frags).
// One barrier per k-iteration.
__global__ __launch_bounds__(256, 4) void mfma_score4_kernel(
    const float* __restrict__ X, const short* __restrict__ w1s,
    const float* __restrict__ b1, const float* __restrict__ w2,
    const float* __restrict__ b2, float* __restrict__ out)
{
    __shared__ __attribute__((aligned(16))) short As[2][1024];  // 2 x 2 KB bf16
    __shared__ float part[4][32];

    const int t = threadIdx.x;
    const int wv = t >> 6, lane = t & 63, lo = lane & 15, q = lane >> 4;
    const long row0 = (long)blockIdx.x * 32;

    f32x4 acc[2][4];
#pragma unroll
    for (int i = 0; i < 2; i++)
#pragma unroll
        for (int j = 0; j < 4; j++) acc[i][j] = (f32x4){0.f, 0.f, 0.f, 0.f};

    // staging: chunk c = t>>1 (c = rt*64 + q*16 + lo), half = t&1
    const int c = t >> 1, half = t & 1;
    const int srow = ((c >> 6) << 4) + (c & 15);
    const int skofs = ((c >> 4) & 3) * 8 + half * 4;
    const float* xs = X + (row0 + srow) * HH + skofs;
    short* const dst0 = &As[0][c * 8 + half * 4];
    short* const dst1 = &As[1][c * 8 + half * 4];
    // B: wave wv, frag ct: lane(q,lo) -> n = wv*64+ct*16+lo, k = kb*32+q*8
    const short* wp = w1s + (wv * 64 + lo) * 32 + q * 8;

    // prologue: stage kb=0 -> buf0, B frags kb=0
    {
        float4 v = *(const float4*)xs;
        unsigned u0 = pk2bf(v.x, v.y), u1 = pk2bf(v.z, v.w);
        ((unsigned*)dst0)[0] = u0; ((unsigned*)dst0)[1] = u1;
    }
    bf16x8 bA[4], bB[4];
#pragma unroll
    for (int ct = 0; ct < 4; ct++)
        bA[ct] = *(const bf16x8*)(wp + ct * 512);
    __syncthreads();

    for (int kb = 0; kb < 32; kb += 2) {
        {   // stage kb+1 -> buf1, load bB(kb+1); compute kb from buf0 w/ bA
            float4 v = *(const float4*)(xs + (kb + 1) * 32);
#pragma unroll
            for (int ct = 0; ct < 4; ct++)
                bB[ct] = *(const bf16x8*)(wp + (kb + 1) * 8192 + ct * 512);
            bf16x8 af[2];
#pragma unroll
            for (int rt = 0; rt < 2; rt++)
                af[rt] = *(bf16x8*)(&As[0][(rt * 64 + q * 16 + lo) * 8]);
#pragma unroll
            for (int rt = 0; rt < 2; rt++)
#pragma unroll
                for (int ct = 0; ct < 4; ct++)
                    acc[rt][ct] = __builtin_amdgcn_mfma_f32_16x16x32_bf16(
                        af[rt], bA[ct], acc[rt][ct], 0, 0, 0);
            unsigned u0 = pk2bf(v.x, v.y), u1 = pk2bf(v.z, v.w);
            ((unsigned*)dst1)[0] = u0; ((unsigned*)dst1)[1] = u1;
        }
        __syncthreads();
        {   // stage kb+2 -> buf0, load bA(kb+2); compute kb+1 from buf1 w/ bB
            const int k2 = (kb + 2 < 32) ? kb + 2 : 31;   // dummy on last iter
            float4 v = *(const float4*)(xs + k2 * 32);
#pragma unroll
            for (int ct = 0; ct < 4; ct++)
                bA[ct] = *(const bf16x8*)(wp + k2 * 8192 + ct * 512);
            bf16x8 af[2];
#pragma unroll
            for (int rt = 0; rt < 2; rt++)
                af[rt] = *(bf16x8*)(&As[1][(rt * 64 + q * 16 + lo) * 8]);
#pragma unroll
            for (int rt = 0; rt < 2; rt++)
#pragma unroll
                for (int ct = 0; ct < 4; ct++)
                    acc[rt][ct] = __builtin_amdgcn_mfma_f32_16x16x32_bf16(
                        af[rt], bB[ct], acc[rt][ct], 0, 0, 0);
            unsigned u0 = pk2bf(v.x, v.y), u1 = pk2bf(v.z, v.w);
            ((unsigned*)dst0)[0] = u0; ((unsigned*)dst0)[1] = u1;
        }
        __syncthreads();
    }

    // epilogue: rowpart[rt][r] = sum_c tanh(acc + b1[c]) * w2[c]
    float rowpart[2][4];
#pragma unroll
    for (int rt = 0; rt < 2; rt++)
#pragma unroll
        for (int r = 0; r < 4; r++) rowpart[rt][r] = 0.f;
#pragma unroll
    for (int ct = 0; ct < 4; ct++) {
        const int cc = wv * 64 + ct * 16 + lo;
        const float b1c = b1[cc], w2c = w2[cc];
#pragma unroll
        for (int rt = 0; rt < 2; rt++)
#pragma unroll
            for (int r = 0; r < 4; r++)
                rowpart[rt][r] += tanhf(acc[rt][ct][r] + b1c) * w2c;
    }
#pragma unroll
    for (int rt = 0; rt < 2; rt++)
#pragma unroll
        for (int r = 0; r < 4; r++) {
            float v = rowpart[rt][r];
            v += __shfl_down(v, 8, 64);
            v += __shfl_down(v, 4, 64);
            v += __shfl_down(v, 2, 64);
            v += __shfl_down(v, 1, 64);
            rowpart[rt][r] = v;   // valid where lo==0
        }
    if (lo == 0)
#pragma unroll
        for (int rt = 0; rt < 2; rt++)
#pragma unroll
            for (int r = 0; r < 4; r++)
                part[wv][rt * 16 + q * 4 + r] = rowpart[rt][r];
    __syncthreads();
    if (t < 32)
        out[row0 + t] = part[0][t] + part[1][t] + part[2][t] + part[3][t] + b2[0];
}

// Per (b,k): masked max + denom; write normalized wtok; zero embed row;
// k==0 also zeroes wtok[0, start).
__global__ __launch_bounds__(256) void block_stats_kernel(
    const float* __restrict__ scores, const int* __restrict__ mask,
    const int* __restrict__ bnd, float* __restrict__ bden,
    float* __restrict__ wtok, float* __restrict__ embed)
{
    const int b = blockIdx.x >> 6, k = blockIdx.x & 63;
    const int start = bnd[b * KK + k];
    const int end = (k == KK - 1) ? SS : bnd[b * KK + k + 1];
    const int tid = threadIdx.x;
    __shared__ float r[4];
    __shared__ float mshared, dshared;

    // zero this block's embed row (embed kernel runs after us)
    *((float4*)(embed + (long)blockIdx.x * HH) + tid) = (float4){0.f, 0.f, 0.f, 0.f};
    // zero the uncovered wtok prefix
    if (k == 0)
        for (int s = tid; s < start; s += 256) wtok[b * SS + s] = 0.f;

    float m = NEGF;
    for (int s = start + tid; s < end; s += 256)
        if (mask[b * SS + s] == 1) m = fmaxf(m, scores[b * SS + s]);
    for (int off = 32; off > 0; off >>= 1) m = fmaxf(m, __shfl_down(m, off, 64));
    if ((tid & 63) == 0) r[tid >> 6] = m;
    __syncthreads();
    if (tid == 0) mshared = fmaxf(fmaxf(r[0], r[1]), fmaxf(r[2], r[3]));
    __syncthreads();
    m = mshared;

    float d = 0.f;
    for (int s = start + tid; s < end; s += 256)
        if (mask[b * SS + s] == 1) d += expf(scores[b * SS + s] - m);
    for (int off = 32; off > 0; off >>= 1) d += __shfl_down(d, off, 64);
    __syncthreads();
    if ((tid & 63) == 0) r[tid >> 6] = d;
    __syncthreads();
    if (tid == 0) {
        float den = r[0] + r[1] + r[2] + r[3];
        bden[blockIdx.x] = den;
        dshared = (den > 0.f) ? 1.f / fmaxf(den, 1e-30f) : 0.f;
    }
    __syncthreads();
    const float inv = dshared;
    for (int s = start + tid; s < end; s += 256)
        wtok[b * SS + s] = (mask[b * SS + s] == 1) ? expf(scores[b * SS + s] - m) * inv : 0.f;
}

// Weighted accumulation: grid = B x (S/16) (2048: 8 WG/CU); thread t owns
// h = t, t+256, t+512, t+768 (lane-coalesced loads AND atomics). wtok chunk
// pre-staged in LDS; fast path when chunk crosses no boundary.
#define TCH 16
__global__ __launch_bounds__(256) void block_embed4_kernel(
    const float* __restrict__ hidden, const float* __restrict__ wtok,
    const int* __restrict__ bnd, float* __restrict__ embed)
{
    const int b = blockIdx.x >> 8;          // 256 chunks per batch
    const int ch = blockIdx.x & 255;
    const int t = threadIdx.x;
    __shared__ int bsh[KK];
    __shared__ float wsh[TCH];
    const int s0 = ch * TCH, s1 = s0 + TCH;
    if (t < KK) bsh[t] = bnd[b * KK + t];
    if (t >= 64 && t < 64 + TCH) wsh[t - 64] = wtok[b * SS + s0 + (t - 64)];
    __syncthreads();

    int cur = -1;
#pragma unroll
    for (int i = 0; i < KK; i++) cur = (bsh[i] <= s0) ? i : cur;
    const int nxt = (cur + 1 < KK) ? bsh[cur + 1] : INT_MAX;   // uniform

    const float* hr0 = hidden + ((long)b * SS + s0) * HH + t;
    float a0 = 0.f, a1 = 0.f, a2 = 0.f, a3 = 0.f;

    if (nxt >= s1 && cur >= 0) {
        // fast path: whole chunk in one block, branch-free
#pragma unroll
        for (int i = 0; i < TCH; i++) {
            const float w = wsh[i];
            const float* hr = hr0 + (long)i * HH;
            a0 = fmaf(w, hr[0], a0);
            a1 = fmaf(w, hr[256], a1);
            a2 = fmaf(w, hr[512], a2);
            a3 = fmaf(w, hr[768], a3);
        }
        float* e = embed + ((long)b * KK + cur) * HH;
        atomicAdd(e + t, a0); atomicAdd(e + t + 256, a1);
        atomicAdd(e + t + 512, a2); atomicAdd(e + t + 768, a3);
        return;
    }

    bool any = false;
    for (int s = s0; s < s1; s++) {
        while (cur + 1 < KK && bsh[cur + 1] <= s) {
            if (any) {
                float* e = embed + ((long)b * KK + cur) * HH;
                atomicAdd(e + t, a0); atomicAdd(e + t + 256, a1);
                atomicAdd(e + t + 512, a2); atomicAdd(e + t + 768, a3);
                a0 = a1 = a2 = a3 = 0.f; any = false;
            }
            cur++;
        }
        if (cur < 0) continue;
        const float w = wsh[s - s0];
        const float* hr = hr0 + (long)(s - s0) * HH;
        a0 = fmaf(w, hr[0], a0);
        a1 = fmaf(w, hr[256], a1);
        a2 = fmaf(w, hr[512], a2);
        a3 = fmaf(w, hr[768], a3);
        any = true;
    }
    if (any) {
        float* e = embed + ((long)b * KK + cur) * HH;
        atomicAdd(e + t, a0); atomicAdd(e + t + 256, a1);
        atomicAdd(e + t + 512, a2); atomicAdd(e + t + 768, a3);
    }
}

// Fused finalize A+B (grid B*8): block softmax -> func slice (128 h) in LDS ->
// partial GEMV -> osum[(b*8+hc)*EE + e] (non-atomic partials).
__global__ __launch_bounds__(256) void finalize_ab_kernel(
    const float* __restrict__ embed, const float* __restrict__ bscores,
    const float* __restrict__ bden, const float* __restrict__ out_w,
    float* __restrict__ osum)
{
    const int b = blockIdx.x >> 3, hc = blockIdx.x & 7;
    const int t = threadIdx.x;
    __shared__ float bw[KK];
    __shared__ float fpart[2][128];
    __shared__ float fsh[128];

    if (t < KK) {   // wave 0
        float s = (bden[b * KK + t] > 0.f) ? bscores[b * KK + t] : NEGF;
        float m = s;
        for (int off = 32; off > 0; off >>= 1) m = fmaxf(m, __shfl_xor(m, off, 64));
        float e = expf(s - m);
        float d = e;
        for (int off = 32; off > 0; off >>= 1) d += __shfl_xor(d, off, 64);
        bw[t] = e / d;
    }
    __syncthreads();

    {   // func slice: h = hc*128 + (t&127), k-half = t>>7
        const int hh = t & 127, kh = t >> 7;
        const float* ep = embed + ((long)b * KK + kh * 32) * HH + hc * 128 + hh;
        float f = 0.f;
#pragma unroll 8
        for (int k2 = 0; k2 < 32; k2++)
            f = fmaf(bw[kh * 32 + k2], ep[(long)k2 * HH], f);
        fpart[kh][hh] = f;
    }
    __syncthreads();
    if (t < 128) fsh[t] = fpart[0][t] + fpart[1][t];
    __syncthreads();

    float acc = 0.f;
    const float* wpp = out_w + (long)(hc * 128) * EE + t;
#pragma unroll 8
    for (int h = 0; h < 128; h++)
        acc = fmaf(fsh[h], wpp[(long)h * EE], acc);
    osum[(long)(b * 8 + hc) * EE + t] = acc;
}

// finalize C (grid B): reduce 8 partials + bias + L2 normalize
__global__ __launch_bounds__(256) void finalize_c_kernel(
    const float* __restrict__ osum, const float* __restrict__ out_b,
    float* __restrict__ outp)
{
    const int b = blockIdx.x, t = threadIdx.x;
    __shared__ float r4[4];
    float o = out_b[t];
#pragma unroll
    for (int hc = 0; hc < 8; hc++)
        o += osum[(long)(b * 8 + hc) * EE + t];
    float sq = o * o;
    for (int off = 32; off > 0; off >>= 1) sq += __shfl_down(sq, off, 64);
    if ((t & 63) == 0) r4[t >> 6] = sq;
    __syncthreads();
    const float nrm = sqrtf(r4[0] + r4[1] + r4[2] + r4[3]);
    outp[b * EE + t] = o / fmaxf(nrm, 1e-12f);
}

extern "C" void kernel_launch(void* const* d_in, const int* in_sizes, int n_in,
                              void* d_out, int out_size, void* d_ws, size_t ws_size,
                              hipStream_t stream) {
    const float* hidden  = (const float*)d_in[0];
    const int*   mask    = (const int*)  d_in[1];
    const int*   bnd     = (const int*)  d_in[2];
    const float* tok_w1  = (const float*)d_in[3];
    const float* tok_b1  = (const float*)d_in[4];
    const float* tok_w2  = (const float*)d_in[5];
    const float* tok_b2  = (const float*)d_in[6];
    const float* blk_w1  = (const float*)d_in[7];
    const float* blk_b1  = (const float*)d_in[8];
    const float* blk_w2  = (const float*)d_in[9];
    const float* blk_b2  = (const float*)d_in[10];
    const float* out_w   = (const float*)d_in[11];
    const float* out_b   = (const float*)d_in[12];

    float* ws      = (float*)d_ws;
    float* wtok    = ws;                       // [32768]
    float* embed   = ws + 32768;               // [524288]
    float* scores  = ws + 557056;              // [32768]
    float* bden    = ws + 589824;              // [512]
    float* bscores = ws + 590336;              // [512]
    float* osum    = ws + 590848;              // [16384]
    short* w1s_tok = (short*)(ws + 607232);    // [262144] bf16
    short* w1s_blk = w1s_tok + 262144;         // [262144] bf16

    convert_both_kernel<<<64, 256, 0, stream>>>(tok_w1, blk_w1, w1s_tok, w1s_blk);
    mfma_score4_kernel<<<BB * SS / 32, 256, 0, stream>>>(
        hidden, w1s_tok, tok_b1, tok_w2, tok_b2, scores);
    block_stats_kernel<<<BB * KK, 256, 0, stream>>>(
        scores, mask, bnd, bden, wtok, embed);
    block_embed4_kernel<<<BB * SS / TCH, 256, 0, stream>>>(hidden, wtok, bnd, embed);
    mfma_score4_kernel<<<BB * KK / 32, 256, 0, stream>>>(
        embed, w1s_blk, blk_b1, blk_w2, blk_b2, bscores);
    finalize_ab_kernel<<<BB * 8, 256, 0, stream>>>(
        embed, bscores, bden, out_w, osum);
    finalize_c_kernel<<<BB, 256, 0, stream>>>(osum, out_b, (float*)d_out);
}